// Round 11
// baseline (581.344 us; speedup 1.0000x reference)
//
#include <hip/hip_runtime.h>
#include <hip/hip_bf16.h>
#include <stdint.h>

#define KTOT 8192
#define BM 64
#define BK 128
#define KSPLIT 4
#define KCHUNK (KTOT / KSPLIT)   // 2048
#define NIT (KCHUNK / BK)        // 16
#define TILE_BYTES (BM * BK * 2) // 16 KiB blocked-A tile image

typedef __attribute__((ext_vector_type(8))) __bf16 bf16x8;
typedef __attribute__((ext_vector_type(4))) float f32x4;

__device__ __forceinline__ unsigned short f2bf(float f) {
  union { float f; unsigned int u; } a;
  a.f = f;
  unsigned int r = (a.u + 0x7fffu + ((a.u >> 16) & 1u)) >> 16;
  return (unsigned short)r;
}

__device__ __forceinline__ uint2 pack4(f32x4 v) {
  union { unsigned short h[4]; uint2 u; } pk;
  pk.h[0] = f2bf(v[0]); pk.h[1] = f2bf(v[1]);
  pk.h[2] = f2bf(v[2]); pk.h[3] = f2bf(v[3]);
  return pk.u;
}

// Barrier that drains LDS only — global prefetches stay in flight (T4).
__device__ __forceinline__ void block_bar() {
  asm volatile("s_waitcnt lgkmcnt(0)" ::: "memory");
  __builtin_amdgcn_s_barrier();
  __builtin_amdgcn_sched_barrier(0);
}

// x [8192][64] f32  ->  xt [64][8192] bf16 (transposed)
__global__ __launch_bounds__(256) void xpose_f32_bf16(const float* __restrict__ x,
                                                      __hip_bfloat16* __restrict__ xt) {
  __shared__ unsigned short tile[64][72];
  const int r0 = blockIdx.x * 64;
  const int t = threadIdx.x;
  const int a = t >> 4;
  const int c4 = (t & 15) * 4;
#pragma unroll
  for (int rep = 0; rep < 4; ++rep) {
    int r = a + rep * 16;
    f32x4 v = __builtin_nontemporal_load(
        reinterpret_cast<const f32x4*>(x + (size_t)(r0 + r) * 64 + c4));
    tile[c4 + 0][r] = f2bf(v[0]);
    tile[c4 + 1][r] = f2bf(v[1]);
    tile[c4 + 2][r] = f2bf(v[2]);
    tile[c4 + 3][r] = f2bf(v[3]);
  }
  __syncthreads();
#pragma unroll
  for (int rep = 0; rep < 4; ++rep) {
    int j = a + rep * 16;
    uint2 v = *reinterpret_cast<const uint2*>(&tile[j][c4]);
    *reinterpret_cast<uint2*>((unsigned short*)xt + (size_t)j * KTOT + r0 + c4) = v;
  }
}

// R9 GEMM (best): part[kc][col][row] partials of C = A @ B, BT[128][8192] bf16.
// A reg->bf16->LDS (XOR swizzle) dbuf; B direct global->reg; lgkm-only
// barriers; K-phase rotation. WBLK=1 additionally stores each packed bf16
// LDS tile image to ablk (blocked A for a later pass).
template <int WBLK>
__global__ __launch_bounds__(512, 4) void gemm_part(
    const float* __restrict__ A, const __hip_bfloat16* __restrict__ BTv,
    float* __restrict__ part, unsigned char* __restrict__ ablk) {
  constexpr int SZ_A = BM * BK * 2;   // 16 KiB
  __shared__ __align__(16) unsigned char smem[2 * SZ_A];
  const unsigned short* BT = (const unsigned short*)BTv;

  const int bid = blockIdx.x;
  const int kc = (bid & 7) >> 1;                 // XCD-affine K-chunk
  const int mblk = ((bid >> 3) << 1) | (bid & 1);
  const int r0 = mblk * BM;
  const int kbase = kc * KCHUNK;
  const int it0 = mblk & (NIT - 1);              // K-phase rotation

  const int t = threadIdx.x;
  const int l = t & 63;
  const int w = t >> 6;

  const float* aptr[4];
  int loff[4];
#pragma unroll
  for (int r = 0; r < 4; ++r) {
    int idx = t + r * 512;
    int m = idx >> 5, c4 = idx & 31;
    aptr[r] = A + (size_t)(r0 + m) * KTOT + kbase + c4 * 4;
    loff[r] = m * 256 + ((c4 * 8) ^ ((m & 7) << 4));
  }
  unsigned char* tb0 =
      WBLK ? ablk + (size_t)(mblk * KSPLIT + kc) * NIT * TILE_BYTES : nullptr;

  const int lr = l & 15;
  const int g = l >> 4;
  const int col = w * 16 + lr;
  const unsigned short* bptr = BT + (size_t)col * KTOT + kbase + g * 8;
  const int asw = (lr & 7) << 4;

  f32x4 acc[4];
  const f32x4 fzero = {0.f, 0.f, 0.f, 0.f};
#pragma unroll
  for (int mt = 0; mt < 4; ++mt) acc[mt] = fzero;

  f32x4 av0[4], av1[4];
  bf16x8 Bf0[4], Bf1[4];
  unsigned char* lds0 = smem;
  unsigned char* lds1 = smem + SZ_A;

  auto kof = [&](int s) { return ((s + it0) & (NIT - 1)) * BK; };

#define LOAD_A(AV, K0)                                                        \
  _Pragma("unroll") for (int r = 0; r < 4; ++r)                               \
      AV[r] = __builtin_nontemporal_load(                                     \
          reinterpret_cast<const f32x4*>(aptr[r] + (K0)));
#define LOAD_B(BF, K0)                                                        \
  _Pragma("unroll") for (int ks = 0; ks < 4; ++ks)                            \
      BF[ks] = *reinterpret_cast<const bf16x8*>(bptr + (K0) + ks * 32);
#define WRITE_A(LDS, AV, RS)                                                  \
  _Pragma("unroll") for (int r = 0; r < 4; ++r) {                             \
    uint2 pk_ = pack4(AV[r]);                                                 \
    *reinterpret_cast<uint2*>((LDS) + loff[r]) = pk_;                         \
    if constexpr (WBLK)                                                       \
      *reinterpret_cast<uint2*>(tb0 + (size_t)(RS) * TILE_BYTES + loff[r]) =  \
          pk_;                                                                \
  }
#define COMPUTE(LDS, BF)                                                      \
  _Pragma("unroll") for (int ks = 0; ks < 4; ++ks) {                          \
    _Pragma("unroll") for (int mt = 0; mt < 4; ++mt) {                        \
      bf16x8 af_ = *reinterpret_cast<const bf16x8*>(                          \
          (LDS) + (mt * 16 + lr) * 256 + ((ks * 64 + g * 16) ^ asw));         \
      acc[mt] = __builtin_amdgcn_mfma_f32_16x16x32_bf16(af_, BF[ks], acc[mt], \
                                                        0, 0, 0);             \
    }                                                                         \
  }

  LOAD_A(av0, kof(0)); LOAD_B(Bf0, kof(0));
  LOAD_A(av1, kof(1)); LOAD_B(Bf1, kof(1));
  WRITE_A(lds0, av0, it0);
  block_bar();

#pragma unroll 1
  for (int s = 0; s < NIT; s += 2) {
    if (s + 1 < NIT) { WRITE_A(lds1, av1, (s + 1 + it0) & (NIT - 1)); }
    if (s + 2 < NIT) { LOAD_A(av0, kof(s + 2)); }
    COMPUTE(lds0, Bf0);
    if (s + 2 < NIT) { LOAD_B(Bf0, kof(s + 2)); }
    if (s + 1 < NIT) block_bar();
    if (s + 1 < NIT) {
      if (s + 2 < NIT) { WRITE_A(lds0, av0, (s + 2 + it0) & (NIT - 1)); }
      if (s + 3 < NIT) { LOAD_A(av1, kof(s + 3)); }
      COMPUTE(lds1, Bf1);
      if (s + 3 < NIT) { LOAD_B(Bf1, kof(s + 3)); }
      if (s + 2 < NIT) block_bar();
    }
  }

  float* pp = part + (size_t)(kc * 128 + col) * KTOT + r0 + g * 4;
#pragma unroll
  for (int mt = 0; mt < 4; ++mt)
    __builtin_nontemporal_store(acc[mt], reinterpret_cast<f32x4*>(pp + mt * 16));
#undef LOAD_A
#undef WRITE_A
}

// G3 variant: A comes from the blocked bf16 tile images written by G1
// (dense 16 KB contiguous per tile, plain loads). Structure otherwise = R9.
__global__ __launch_bounds__(512, 4) void gemm_blocked(
    const unsigned char* __restrict__ ablk, const __hip_bfloat16* __restrict__ BTv,
    float* __restrict__ part) {
  constexpr int SZ_A = BM * BK * 2;
  __shared__ __align__(16) unsigned char smem[2 * SZ_A];
  const unsigned short* BT = (const unsigned short*)BTv;

  const int bid = blockIdx.x;
  const int kc = (bid & 7) >> 1;
  const int mblk = ((bid >> 3) << 1) | (bid & 1);
  const int r0 = mblk * BM;
  const int kbase = kc * KCHUNK;
  const int it0 = mblk & (NIT - 1);

  const int t = threadIdx.x;
  const int l = t & 63;
  const int w = t >> 6;

  int loff[4];
#pragma unroll
  for (int r = 0; r < 4; ++r) {
    int idx = t + r * 512;
    int m = idx >> 5, c4 = idx & 31;
    loff[r] = m * 256 + ((c4 * 8) ^ ((m & 7) << 4));
  }
  const unsigned char* tb0 =
      ablk + (size_t)(mblk * KSPLIT + kc) * NIT * TILE_BYTES;

  const int lr = l & 15;
  const int g = l >> 4;
  const int col = w * 16 + lr;
  const unsigned short* bptr = BT + (size_t)col * KTOT + kbase + g * 8;
  const int asw = (lr & 7) << 4;

  f32x4 acc[4];
  const f32x4 fzero = {0.f, 0.f, 0.f, 0.f};
#pragma unroll
  for (int mt = 0; mt < 4; ++mt) acc[mt] = fzero;

  uint2 bv0[4], bv1[4];
  bf16x8 Bf0[4], Bf1[4];
  unsigned char* lds0 = smem;
  unsigned char* lds1 = smem + SZ_A;

  auto kof = [&](int s) { return ((s + it0) & (NIT - 1)) * BK; };
  auto rs = [&](int s) { return (s + it0) & (NIT - 1); };

#define LOAD_A(BV, RS)                                                        \
  _Pragma("unroll") for (int r = 0; r < 4; ++r)                               \
      BV[r] = *reinterpret_cast<const uint2*>(                                \
          tb0 + (size_t)(RS) * TILE_BYTES + loff[r]);
#define LOAD_B(BF, K0)                                                        \
  _Pragma("unroll") for (int ks = 0; ks < 4; ++ks)                            \
      BF[ks] = *reinterpret_cast<const bf16x8*>(bptr + (K0) + ks * 32);
#define WRITE_A(LDS, BV)                                                      \
  _Pragma("unroll") for (int r = 0; r < 4; ++r)                               \
      *reinterpret_cast<uint2*>((LDS) + loff[r]) = BV[r];
#define COMPUTE(LDS, BF)                                                      \
  _Pragma("unroll") for (int ks = 0; ks < 4; ++ks) {                          \
    _Pragma("unroll") for (int mt = 0; mt < 4; ++mt) {                        \
      bf16x8 af_ = *reinterpret_cast<const bf16x8*>(                          \
          (LDS) + (mt * 16 + lr) * 256 + ((ks * 64 + g * 16) ^ asw));         \
      acc[mt] = __builtin_amdgcn_mfma_f32_16x16x32_bf16(af_, BF[ks], acc[mt], \
                                                        0, 0, 0);             \
    }                                                                         \
  }

  LOAD_A(bv0, rs(0)); LOAD_B(Bf0, kof(0));
  LOAD_A(bv1, rs(1)); LOAD_B(Bf1, kof(1));
  WRITE_A(lds0, bv0);
  block_bar();

#pragma unroll 1
  for (int s = 0; s < NIT; s += 2) {
    if (s + 1 < NIT) { WRITE_A(lds1, bv1); }
    if (s + 2 < NIT) { LOAD_A(bv0, rs(s + 2)); }
    COMPUTE(lds0, Bf0);
    if (s + 2 < NIT) { LOAD_B(Bf0, kof(s + 2)); }
    if (s + 1 < NIT) block_bar();
    if (s + 1 < NIT) {
      if (s + 2 < NIT) { WRITE_A(lds0, bv0); }
      if (s + 3 < NIT) { LOAD_A(bv1, rs(s + 3)); }
      COMPUTE(lds1, Bf1);
      if (s + 3 < NIT) { LOAD_B(Bf1, kof(s + 3)); }
      if (s + 2 < NIT) block_bar();
    }
  }

  float* pp = part + (size_t)(kc * 128 + col) * KTOT + r0 + g * 4;
#pragma unroll
  for (int mt = 0; mt < 4; ++mt)
    __builtin_nontemporal_store(acc[mt], reinterpret_cast<f32x4*>(pp + mt * 16));
#undef LOAD_A
#undef LOAD_B
#undef WRITE_A
#undef COMPUTE
}

// Combine KSPLIT partials + epilogue, separate halves (lo: cols 0-63, hi: 64-127).
__global__ __launch_bounds__(256) void reduce_sep(
    const float* __restrict__ part, float* __restrict__ out,
    const float* s_lo_p, const float* s_hi_p,
    const float* __restrict__ add_ptr, const float* add_s_p,
    __hip_bfloat16* bt_lo, __hip_bfloat16* bt_hi,
    int base_lo, int base_hi, int accum) {
  const int t = threadIdx.x;
  const int col = t & 127;
  const int rbase = blockIdx.x * 32 + (t >> 7) * 16;
  const float* p0 = part + (size_t)col * KTOT + rbase;
  const bool hi = col >= 64;
  const int col64 = hi ? col - 64 : col;
  __hip_bfloat16* bt = hi ? bt_hi : bt_lo;
  const int obase = hi ? base_hi : base_lo;
  const float s = hi ? (s_hi_p ? *s_hi_p : 0.f) : (s_lo_p ? *s_lo_p : 0.f);
  const float was = add_s_p ? *add_s_p : 0.f;
#pragma unroll
  for (int i = 0; i < 4; ++i) {
    f32x4 c = __builtin_nontemporal_load(
        reinterpret_cast<const f32x4*>(p0 + 4 * i));
#pragma unroll
    for (int k = 1; k < KSPLIT; ++k)
      c += __builtin_nontemporal_load(reinterpret_cast<const f32x4*>(
          p0 + (size_t)k * 128 * KTOT + 4 * i));
    if (bt)
      *reinterpret_cast<uint2*>((unsigned short*)bt + (size_t)col64 * KTOT + rbase + 4 * i) =
          pack4(c);
    if (obase >= 0) {
#pragma unroll
      for (int j = 0; j < 4; ++j) {
        int row = rbase + 4 * i + j;
        float v = s * c[j];
        if (add_ptr && !hi) v = fmaf(was, add_ptr[(size_t)row * 64 + col64], v);
        if (accum) v += out[(size_t)row * 128 + obase + col64];
        out[(size_t)row * 128 + obase + col64] = v;
      }
    }
  }
}

// Combine partials + cross-half epilogue: out[:,64+c] = sl*lo[c] + sh*hi[c];
// bt_lo = raw lo (bf16 transposed).
__global__ __launch_bounds__(256) void reduce_comb(
    const float* __restrict__ part, float* __restrict__ out,
    const float* s_lo_p, const float* s_hi_p, __hip_bfloat16* bt_lo) {
  const int t = threadIdx.x;
  const int c = t & 63;
  const int rbase = blockIdx.x * 32 + (t >> 6) * 8;
  const float* pl = part + (size_t)c * KTOT + rbase;
  const float* ph = part + (size_t)(c + 64) * KTOT + rbase;
  const float sl = *s_lo_p, sh = *s_hi_p;
#pragma unroll
  for (int i = 0; i < 2; ++i) {
    f32x4 lo = __builtin_nontemporal_load(reinterpret_cast<const f32x4*>(pl + 4 * i));
    f32x4 hv = __builtin_nontemporal_load(reinterpret_cast<const f32x4*>(ph + 4 * i));
#pragma unroll
    for (int k = 1; k < KSPLIT; ++k) {
      lo += __builtin_nontemporal_load(reinterpret_cast<const f32x4*>(
          pl + (size_t)k * 128 * KTOT + 4 * i));
      hv += __builtin_nontemporal_load(reinterpret_cast<const f32x4*>(
          ph + (size_t)k * 128 * KTOT + 4 * i));
    }
    *reinterpret_cast<uint2*>((unsigned short*)bt_lo + (size_t)c * KTOT + rbase + 4 * i) =
        pack4(lo);
#pragma unroll
    for (int j = 0; j < 4; ++j) {
      int row = rbase + 4 * i + j;
      out[(size_t)row * 128 + 64 + c] = sl * lo[j] + sh * hv[j];
    }
  }
}

// DIAGNOSTIC probe: full-row-sweep pattern (BM=32-style GEMM A-read).
// Block b reads rows b*32..+31 in full (32 KB contiguous per row), k-start
// rotated by block. 4 passes alternating A_p/A_n = 1.07 GB. NT templated.
template <int NT>
__global__ __launch_bounds__(512) void seq_probe(
    const float* __restrict__ A0, const float* __restrict__ A1,
    float* __restrict__ sink) {
  const int b = blockIdx.x, t = threadIdx.x;
  const int r = t >> 4, c = t & 15;
  f32x4 acc = {0.f, 0.f, 0.f, 0.f};
#pragma unroll 1
  for (int p = 0; p < 4; ++p) {
    const float* bp = ((p & 1) ? A1 : A0) + (size_t)(b * 32 + r) * KTOT + c * 4;
#pragma unroll 8
    for (int it = 0; it < 128; ++it) {
      int k = ((it + b) & 127) * 64;
      if constexpr (NT)
        acc += __builtin_nontemporal_load(
            reinterpret_cast<const f32x4*>(bp + k));
      else
        acc += *reinterpret_cast<const f32x4*>(bp + k);
    }
  }
  sink[(size_t)b * 512 + t] = acc[0] + acc[1] + acc[2] + acc[3];
}

extern "C" void kernel_launch(void* const* d_in, const int* in_sizes, int n_in,
                              void* d_out, int out_size, void* d_ws, size_t ws_size,
                              hipStream_t stream) {
  const float* A_p = (const float*)d_in[0];
  const float* A_n = (const float*)d_in[1];
  const float* x_p = (const float*)d_in[2];
  const float* x_n = (const float*)d_in[3];
  const float* w_p = (const float*)d_in[4];  // [3]
  const float* w_n = (const float*)d_in[5];  // [3]
  float* out = (float*)d_out;                // [8192][128]

  // ws layout:
  //   BTbig [192][8192] bf16 (3 MiB) | B3T [128][8192] bf16 (2 MiB)
  //   part  [KSPLIT][128][8192] f32 (16 MiB)
  //   ablk  blocked bf16 A_p tile images (128 MiB) — if ws_size allows
  __hip_bfloat16* BTbig = (__hip_bfloat16*)d_ws;
  __hip_bfloat16* B3T = BTbig + (size_t)192 * KTOT;
  float* part = (float*)(B3T + (size_t)128 * KTOT);
  unsigned char* ablk = (unsigned char*)(part + (size_t)KSPLIT * 128 * KTOT);
  const size_t base_need = (size_t)192 * KTOT * 2 + (size_t)128 * KTOT * 2 +
                           (size_t)KSPLIT * 128 * KTOT * 4;
  const size_t blk_need = (size_t)KTOT * KTOT * 2;   // 128 MiB
  const bool use_blk = ws_size >= base_need + blk_need;

  xpose_f32_bf16<<<128, 256, 0, stream>>>(x_p, BTbig);
  xpose_f32_bf16<<<128, 256, 0, stream>>>(x_n, BTbig + (size_t)64 * KTOT);

  // G1: [P1|Y1] = A_p @ [x_p|x_n]  (+ emit blocked bf16 A_p)
  if (use_blk)
    gemm_part<1><<<512, 512, 0, stream>>>(A_p, BTbig, part, ablk);
  else
    gemm_part<0><<<512, 512, 0, stream>>>(A_p, BTbig, part, nullptr);
  reduce_sep<<<256, 256, 0, stream>>>(part, out, w_p + 1, nullptr, x_p, w_p + 0,
                                      B3T, BTbig + (size_t)128 * KTOT, 0, -1, 0);

  // G2': [T1|T3] = A_n @ [x_n|Y1]
  gemm_part<0><<<512, 512, 0, stream>>>(A_n, BTbig + (size_t)64 * KTOT, part,
                                        nullptr);
  reduce_comb<<<256, 256, 0, stream>>>(part, out, w_n + 0, w_n + 2,
                                       B3T + (size_t)64 * KTOT);

  // G3: [P2|T2] = A_p @ [P1|T1] — from blocked bf16 A_p if available
  if (use_blk)
    gemm_blocked<<<512, 512, 0, stream>>>(ablk, B3T, part);
  else
    gemm_part<0><<<512, 512, 0, stream>>>(A_p, B3T, part, nullptr);
  reduce_sep<<<256, 256, 0, stream>>>(part, out, w_p + 2, w_n + 1, nullptr, nullptr,
                                      nullptr, nullptr, 0, 64, 1);

  // DIAGNOSTICS (timed, additive): full-row-sweep read pattern, NT vs non-NT.
  seq_probe<1><<<256, 512, 0, stream>>>(A_p, A_n, part);
  seq_probe<0><<<256, 512, 0, stream>>>(A_p, A_n, part + (1 << 20));
}

// Round 12
// 237.977 us; speedup vs baseline: 2.4429x; 2.4429x over previous
//
#include <hip/hip_runtime.h>
#include <hip/hip_bf16.h>
#include <stdint.h>

#define KTOT 8192
#define BM 64
#define BK 128
#define KSPLIT 4
#define KCHUNK (KTOT / KSPLIT)   // 2048
#define NIT (KCHUNK / BK)        // 16
#define TILE_BYTES (BM * BK * 2) // 16 KiB blocked-A tile image

typedef __attribute__((ext_vector_type(8))) __bf16 bf16x8;
typedef __attribute__((ext_vector_type(4))) float f32x4;

__device__ __forceinline__ unsigned short f2bf(float f) {
  union { float f; unsigned int u; } a;
  a.f = f;
  unsigned int r = (a.u + 0x7fffu + ((a.u >> 16) & 1u)) >> 16;
  return (unsigned short)r;
}

__device__ __forceinline__ uint2 pack4(f32x4 v) {
  union { unsigned short h[4]; uint2 u; } pk;
  pk.h[0] = f2bf(v[0]); pk.h[1] = f2bf(v[1]);
  pk.h[2] = f2bf(v[2]); pk.h[3] = f2bf(v[3]);
  return pk.u;
}

// Barrier that drains LDS only — global prefetches stay in flight (T4).
__device__ __forceinline__ void block_bar() {
  asm volatile("s_waitcnt lgkmcnt(0)" ::: "memory");
  __builtin_amdgcn_s_barrier();
  __builtin_amdgcn_sched_barrier(0);
}

// x [8192][64] f32  ->  xt [64][8192] bf16 (transposed)
__global__ __launch_bounds__(256) void xpose_f32_bf16(const float* __restrict__ x,
                                                      __hip_bfloat16* __restrict__ xt) {
  __shared__ unsigned short tile[64][72];
  const int r0 = blockIdx.x * 64;
  const int t = threadIdx.x;
  const int a = t >> 4;
  const int c4 = (t & 15) * 4;
#pragma unroll
  for (int rep = 0; rep < 4; ++rep) {
    int r = a + rep * 16;
    f32x4 v = __builtin_nontemporal_load(
        reinterpret_cast<const f32x4*>(x + (size_t)(r0 + r) * 64 + c4));
    tile[c4 + 0][r] = f2bf(v[0]);
    tile[c4 + 1][r] = f2bf(v[1]);
    tile[c4 + 2][r] = f2bf(v[2]);
    tile[c4 + 3][r] = f2bf(v[3]);
  }
  __syncthreads();
#pragma unroll
  for (int rep = 0; rep < 4; ++rep) {
    int j = a + rep * 16;
    uint2 v = *reinterpret_cast<const uint2*>(&tile[j][c4]);
    *reinterpret_cast<uint2*>((unsigned short*)xt + (size_t)j * KTOT + r0 + c4) = v;
  }
}

// R9 GEMM: part[kc][col][row] partials of C = A @ B, BT[128][8192] bf16.
// A reg->bf16->LDS (XOR swizzle) dbuf; B direct global->reg; lgkm-only
// barriers; K-phase rotation. WBLK=1 additionally stores each packed bf16
// LDS tile image to ablk (blocked A, read densely by gemm_blocked later).
template <int WBLK>
__global__ __launch_bounds__(512, 4) void gemm_part(
    const float* __restrict__ A, const __hip_bfloat16* __restrict__ BTv,
    float* __restrict__ part, unsigned char* __restrict__ ablk) {
  constexpr int SZ_A = BM * BK * 2;   // 16 KiB
  __shared__ __align__(16) unsigned char smem[2 * SZ_A];
  const unsigned short* BT = (const unsigned short*)BTv;

  const int bid = blockIdx.x;
  const int kc = (bid & 7) >> 1;                 // XCD-affine K-chunk
  const int mblk = ((bid >> 3) << 1) | (bid & 1);
  const int r0 = mblk * BM;
  const int kbase = kc * KCHUNK;
  const int it0 = mblk & (NIT - 1);              // K-phase rotation

  const int t = threadIdx.x;
  const int l = t & 63;
  const int w = t >> 6;

  const float* aptr[4];
  int loff[4];
#pragma unroll
  for (int r = 0; r < 4; ++r) {
    int idx = t + r * 512;
    int m = idx >> 5, c4 = idx & 31;
    aptr[r] = A + (size_t)(r0 + m) * KTOT + kbase + c4 * 4;
    loff[r] = m * 256 + ((c4 * 8) ^ ((m & 7) << 4));
  }
  unsigned char* tb0 =
      WBLK ? ablk + (size_t)(mblk * KSPLIT + kc) * NIT * TILE_BYTES : nullptr;

  const int lr = l & 15;
  const int g = l >> 4;
  const int col = w * 16 + lr;
  const unsigned short* bptr = BT + (size_t)col * KTOT + kbase + g * 8;
  const int asw = (lr & 7) << 4;

  f32x4 acc[4];
  const f32x4 fzero = {0.f, 0.f, 0.f, 0.f};
#pragma unroll
  for (int mt = 0; mt < 4; ++mt) acc[mt] = fzero;

  f32x4 av0[4], av1[4];
  bf16x8 Bf0[4], Bf1[4];
  unsigned char* lds0 = smem;
  unsigned char* lds1 = smem + SZ_A;

  auto kof = [&](int s) { return ((s + it0) & (NIT - 1)) * BK; };

#define LOAD_A(AV, K0)                                                        \
  _Pragma("unroll") for (int r = 0; r < 4; ++r)                               \
      AV[r] = __builtin_nontemporal_load(                                     \
          reinterpret_cast<const f32x4*>(aptr[r] + (K0)));
#define LOAD_B(BF, K0)                                                        \
  _Pragma("unroll") for (int ks = 0; ks < 4; ++ks)                            \
      BF[ks] = *reinterpret_cast<const bf16x8*>(bptr + (K0) + ks * 32);
#define WRITE_A(LDS, AV, RS)                                                  \
  _Pragma("unroll") for (int r = 0; r < 4; ++r) {                             \
    uint2 pk_ = pack4(AV[r]);                                                 \
    *reinterpret_cast<uint2*>((LDS) + loff[r]) = pk_;                         \
    if constexpr (WBLK)                                                       \
      *reinterpret_cast<uint2*>(tb0 + (size_t)(RS) * TILE_BYTES + loff[r]) =  \
          pk_;                                                                \
  }
#define COMPUTE(LDS, BF)                                                      \
  _Pragma("unroll") for (int ks = 0; ks < 4; ++ks) {                          \
    _Pragma("unroll") for (int mt = 0; mt < 4; ++mt) {                        \
      bf16x8 af_ = *reinterpret_cast<const bf16x8*>(                          \
          (LDS) + (mt * 16 + lr) * 256 + ((ks * 64 + g * 16) ^ asw));         \
      acc[mt] = __builtin_amdgcn_mfma_f32_16x16x32_bf16(af_, BF[ks], acc[mt], \
                                                        0, 0, 0);             \
    }                                                                         \
  }

  LOAD_A(av0, kof(0)); LOAD_B(Bf0, kof(0));
  LOAD_A(av1, kof(1)); LOAD_B(Bf1, kof(1));
  WRITE_A(lds0, av0, it0);
  block_bar();

#pragma unroll 1
  for (int s = 0; s < NIT; s += 2) {
    if (s + 1 < NIT) { WRITE_A(lds1, av1, (s + 1 + it0) & (NIT - 1)); }
    if (s + 2 < NIT) { LOAD_A(av0, kof(s + 2)); }
    COMPUTE(lds0, Bf0);
    if (s + 2 < NIT) { LOAD_B(Bf0, kof(s + 2)); }
    if (s + 1 < NIT) block_bar();
    if (s + 1 < NIT) {
      if (s + 2 < NIT) { WRITE_A(lds0, av0, (s + 2 + it0) & (NIT - 1)); }
      if (s + 3 < NIT) { LOAD_A(av1, kof(s + 3)); }
      COMPUTE(lds1, Bf1);
      if (s + 3 < NIT) { LOAD_B(Bf1, kof(s + 3)); }
      if (s + 2 < NIT) block_bar();
    }
  }

  float* pp = part + (size_t)(kc * 128 + col) * KTOT + r0 + g * 4;
#pragma unroll
  for (int mt = 0; mt < 4; ++mt)
    __builtin_nontemporal_store(acc[mt], reinterpret_cast<f32x4*>(pp + mt * 16));
#undef LOAD_A
#undef WRITE_A
}

// G3 variant: A from the blocked bf16 tile images written by G1 — each block
// reads its own 256 KB contiguous slab (few, long streams; L3-friendly).
__global__ __launch_bounds__(512, 4) void gemm_blocked(
    const unsigned char* __restrict__ ablk, const __hip_bfloat16* __restrict__ BTv,
    float* __restrict__ part) {
  constexpr int SZ_A = BM * BK * 2;
  __shared__ __align__(16) unsigned char smem[2 * SZ_A];
  const unsigned short* BT = (const unsigned short*)BTv;

  const int bid = blockIdx.x;
  const int kc = (bid & 7) >> 1;
  const int mblk = ((bid >> 3) << 1) | (bid & 1);
  const int r0 = mblk * BM;
  const int kbase = kc * KCHUNK;
  const int it0 = mblk & (NIT - 1);

  const int t = threadIdx.x;
  const int l = t & 63;
  const int w = t >> 6;

  int loff[4];
#pragma unroll
  for (int r = 0; r < 4; ++r) {
    int idx = t + r * 512;
    int m = idx >> 5, c4 = idx & 31;
    loff[r] = m * 256 + ((c4 * 8) ^ ((m & 7) << 4));
  }
  const unsigned char* tb0 =
      ablk + (size_t)(mblk * KSPLIT + kc) * NIT * TILE_BYTES;

  const int lr = l & 15;
  const int g = l >> 4;
  const int col = w * 16 + lr;
  const unsigned short* bptr = BT + (size_t)col * KTOT + kbase + g * 8;
  const int asw = (lr & 7) << 4;

  f32x4 acc[4];
  const f32x4 fzero = {0.f, 0.f, 0.f, 0.f};
#pragma unroll
  for (int mt = 0; mt < 4; ++mt) acc[mt] = fzero;

  uint2 bv0[4], bv1[4];
  bf16x8 Bf0[4], Bf1[4];
  unsigned char* lds0 = smem;
  unsigned char* lds1 = smem + SZ_A;

  auto kof = [&](int s) { return ((s + it0) & (NIT - 1)) * BK; };
  auto rs = [&](int s) { return (s + it0) & (NIT - 1); };

#define LOAD_A(BV, RS)                                                        \
  _Pragma("unroll") for (int r = 0; r < 4; ++r)                               \
      BV[r] = *reinterpret_cast<const uint2*>(                                \
          tb0 + (size_t)(RS) * TILE_BYTES + loff[r]);
#define LOAD_B(BF, K0)                                                        \
  _Pragma("unroll") for (int ks = 0; ks < 4; ++ks)                            \
      BF[ks] = *reinterpret_cast<const bf16x8*>(bptr + (K0) + ks * 32);
#define WRITE_A(LDS, BV)                                                      \
  _Pragma("unroll") for (int r = 0; r < 4; ++r)                               \
      *reinterpret_cast<uint2*>((LDS) + loff[r]) = BV[r];
#define COMPUTE(LDS, BF)                                                      \
  _Pragma("unroll") for (int ks = 0; ks < 4; ++ks) {                          \
    _Pragma("unroll") for (int mt = 0; mt < 4; ++mt) {                        \
      bf16x8 af_ = *reinterpret_cast<const bf16x8*>(                          \
          (LDS) + (mt * 16 + lr) * 256 + ((ks * 64 + g * 16) ^ asw));         \
      acc[mt] = __builtin_amdgcn_mfma_f32_16x16x32_bf16(af_, BF[ks], acc[mt], \
                                                        0, 0, 0);             \
    }                                                                         \
  }

  LOAD_A(bv0, rs(0)); LOAD_B(Bf0, kof(0));
  LOAD_A(bv1, rs(1)); LOAD_B(Bf1, kof(1));
  WRITE_A(lds0, bv0);
  block_bar();

#pragma unroll 1
  for (int s = 0; s < NIT; s += 2) {
    if (s + 1 < NIT) { WRITE_A(lds1, bv1); }
    if (s + 2 < NIT) { LOAD_A(bv0, rs(s + 2)); }
    COMPUTE(lds0, Bf0);
    if (s + 2 < NIT) { LOAD_B(Bf0, kof(s + 2)); }
    if (s + 1 < NIT) block_bar();
    if (s + 1 < NIT) {
      if (s + 2 < NIT) { WRITE_A(lds0, bv0); }
      if (s + 3 < NIT) { LOAD_A(bv1, rs(s + 3)); }
      COMPUTE(lds1, Bf1);
      if (s + 3 < NIT) { LOAD_B(Bf1, kof(s + 3)); }
      if (s + 2 < NIT) block_bar();
    }
  }

  float* pp = part + (size_t)(kc * 128 + col) * KTOT + r0 + g * 4;
#pragma unroll
  for (int mt = 0; mt < 4; ++mt)
    __builtin_nontemporal_store(acc[mt], reinterpret_cast<f32x4*>(pp + mt * 16));
#undef LOAD_A
#undef LOAD_B
#undef WRITE_A
#undef COMPUTE
}

// Combine KSPLIT partials + epilogue, separate halves (lo: cols 0-63, hi: 64-127).
__global__ __launch_bounds__(256) void reduce_sep(
    const float* __restrict__ part, float* __restrict__ out,
    const float* s_lo_p, const float* s_hi_p,
    const float* __restrict__ add_ptr, const float* add_s_p,
    __hip_bfloat16* bt_lo, __hip_bfloat16* bt_hi,
    int base_lo, int base_hi, int accum) {
  const int t = threadIdx.x;
  const int col = t & 127;
  const int rbase = blockIdx.x * 32 + (t >> 7) * 16;
  const float* p0 = part + (size_t)col * KTOT + rbase;
  const bool hi = col >= 64;
  const int col64 = hi ? col - 64 : col;
  __hip_bfloat16* bt = hi ? bt_hi : bt_lo;
  const int obase = hi ? base_hi : base_lo;
  const float s = hi ? (s_hi_p ? *s_hi_p : 0.f) : (s_lo_p ? *s_lo_p : 0.f);
  const float was = add_s_p ? *add_s_p : 0.f;
#pragma unroll
  for (int i = 0; i < 4; ++i) {
    f32x4 c = __builtin_nontemporal_load(
        reinterpret_cast<const f32x4*>(p0 + 4 * i));
#pragma unroll
    for (int k = 1; k < KSPLIT; ++k)
      c += __builtin_nontemporal_load(reinterpret_cast<const f32x4*>(
          p0 + (size_t)k * 128 * KTOT + 4 * i));
    if (bt)
      *reinterpret_cast<uint2*>((unsigned short*)bt + (size_t)col64 * KTOT + rbase + 4 * i) =
          pack4(c);
    if (obase >= 0) {
#pragma unroll
      for (int j = 0; j < 4; ++j) {
        int row = rbase + 4 * i + j;
        float v = s * c[j];
        if (add_ptr && !hi) v = fmaf(was, add_ptr[(size_t)row * 64 + col64], v);
        if (accum) v += out[(size_t)row * 128 + obase + col64];
        out[(size_t)row * 128 + obase + col64] = v;
      }
    }
  }
}

// Combine partials + cross-half epilogue: out[:,64+c] = sl*lo[c] + sh*hi[c];
// bt_lo = raw lo (bf16 transposed).
__global__ __launch_bounds__(256) void reduce_comb(
    const float* __restrict__ part, float* __restrict__ out,
    const float* s_lo_p, const float* s_hi_p, __hip_bfloat16* bt_lo) {
  const int t = threadIdx.x;
  const int c = t & 63;
  const int rbase = blockIdx.x * 32 + (t >> 6) * 8;
  const float* pl = part + (size_t)c * KTOT + rbase;
  const float* ph = part + (size_t)(c + 64) * KTOT + rbase;
  const float sl = *s_lo_p, sh = *s_hi_p;
#pragma unroll
  for (int i = 0; i < 2; ++i) {
    f32x4 lo = __builtin_nontemporal_load(reinterpret_cast<const f32x4*>(pl + 4 * i));
    f32x4 hv = __builtin_nontemporal_load(reinterpret_cast<const f32x4*>(ph + 4 * i));
#pragma unroll
    for (int k = 1; k < KSPLIT; ++k) {
      lo += __builtin_nontemporal_load(reinterpret_cast<const f32x4*>(
          pl + (size_t)k * 128 * KTOT + 4 * i));
      hv += __builtin_nontemporal_load(reinterpret_cast<const f32x4*>(
          ph + (size_t)k * 128 * KTOT + 4 * i));
    }
    *reinterpret_cast<uint2*>((unsigned short*)bt_lo + (size_t)c * KTOT + rbase + 4 * i) =
        pack4(lo);
#pragma unroll
    for (int j = 0; j < 4; ++j) {
      int row = rbase + 4 * i + j;
      out[(size_t)row * 128 + 64 + c] = sl * lo[j] + sh * hv[j];
    }
  }
}

extern "C" void kernel_launch(void* const* d_in, const int* in_sizes, int n_in,
                              void* d_out, int out_size, void* d_ws, size_t ws_size,
                              hipStream_t stream) {
  const float* A_p = (const float*)d_in[0];
  const float* A_n = (const float*)d_in[1];
  const float* x_p = (const float*)d_in[2];
  const float* x_n = (const float*)d_in[3];
  const float* w_p = (const float*)d_in[4];  // [3]
  const float* w_n = (const float*)d_in[5];  // [3]
  float* out = (float*)d_out;                // [8192][128]

  // ws layout:
  //   BTbig [192][8192] bf16 (3 MiB) | B3T [128][8192] bf16 (2 MiB)
  //   part  [KSPLIT][128][8192] f32 (16 MiB)
  //   ablk  blocked bf16 A_p tile images (128 MiB) — if ws_size allows
  __hip_bfloat16* BTbig = (__hip_bfloat16*)d_ws;
  __hip_bfloat16* B3T = BTbig + (size_t)192 * KTOT;
  float* part = (float*)(B3T + (size_t)128 * KTOT);
  unsigned char* ablk = (unsigned char*)(part + (size_t)KSPLIT * 128 * KTOT);
  const size_t base_need = (size_t)192 * KTOT * 2 + (size_t)128 * KTOT * 2 +
                           (size_t)KSPLIT * 128 * KTOT * 4;
  const size_t blk_need = (size_t)KTOT * KTOT * 2;   // 128 MiB
  const bool use_blk = ws_size >= base_need + blk_need;

  xpose_f32_bf16<<<128, 256, 0, stream>>>(x_p, BTbig);
  xpose_f32_bf16<<<128, 256, 0, stream>>>(x_n, BTbig + (size_t)64 * KTOT);

  // G1: [P1|Y1] = A_p @ [x_p|x_n]  (+ emit blocked bf16 A_p)
  if (use_blk)
    gemm_part<1><<<512, 512, 0, stream>>>(A_p, BTbig, part, ablk);
  else
    gemm_part<0><<<512, 512, 0, stream>>>(A_p, BTbig, part, nullptr);
  reduce_sep<<<256, 256, 0, stream>>>(part, out, w_p + 1, nullptr, x_p, w_p + 0,
                                      B3T, BTbig + (size_t)128 * KTOT, 0, -1, 0);

  // G2': [T1|T3] = A_n @ [x_n|Y1]
  gemm_part<0><<<512, 512, 0, stream>>>(A_n, BTbig + (size_t)64 * KTOT, part,
                                        nullptr);
  reduce_comb<<<256, 256, 0, stream>>>(part, out, w_n + 0, w_n + 2,
                                       B3T + (size_t)64 * KTOT);

  // G3: [P2|T2] = A_p @ [P1|T1] — from blocked bf16 A_p if available
  if (use_blk)
    gemm_blocked<<<512, 512, 0, stream>>>(ablk, B3T, part);
  else
    gemm_part<0><<<512, 512, 0, stream>>>(A_p, B3T, part, nullptr);
  reduce_sep<<<256, 256, 0, stream>>>(part, out, w_p + 2, w_n + 1, nullptr, nullptr,
                                      nullptr, nullptr, 0, 64, 1);
}